// Round 15
// baseline (78.241 us; speedup 1.0000x reference)
//
#include <hip/hip_runtime.h>
#include <hip/hip_bf16.h>

// Problem constants
#define L_SEQ 2048
#define BATCH 2
#define ROWS 4096          // L*B, row index = l*2 + b
#define E 1024
#define NH 16
#define HD 64

typedef __attribute__((ext_vector_type(4))) float f32x4;
typedef __attribute__((ext_vector_type(8))) __bf16 bf16x8;

// XOR swizzle for 128-byte-row LDS tiles (break same-bank column reads)
#define SWZ(byt) ((byt) ^ ((((byt) >> 7) & 7) << 4))

__device__ __forceinline__ void gload16(const void* g, void* l) {
    __builtin_amdgcn_global_load_lds((const __attribute__((address_space(1))) void*)g,
                                     (__attribute__((address_space(3))) void*)l,
                                     16, 0, 0);
}

// ---------------- fused: f32->bf16 convert of q/k/v  +  W transpose to bf16 ----------------
__global__ __launch_bounds__(256) void prep(const float* __restrict__ q,
                                            const float* __restrict__ k,
                                            const float* __restrict__ v,
                                            const float* __restrict__ Wq,
                                            const float* __restrict__ Wk,
                                            const float* __restrict__ Wv,
                                            __bf16* __restrict__ Xb,
                                            __bf16* __restrict__ Wt) {
    const int z = blockIdx.y;
    if (blockIdx.x < 2048) {
        const float* src = (z == 0) ? q : ((z == 1) ? k : v);
        __bf16* dst = Xb + (size_t)z * ROWS * E;
        const size_t i = ((size_t)blockIdx.x * 256 + threadIdx.x) * 8;
        const float4 a = *(const float4*)(src + i);
        const float4 b = *(const float4*)(src + i + 4);
        bf16x8 o;
        o[0] = (__bf16)a.x; o[1] = (__bf16)a.y; o[2] = (__bf16)a.z; o[3] = (__bf16)a.w;
        o[4] = (__bf16)b.x; o[5] = (__bf16)b.y; o[6] = (__bf16)b.z; o[7] = (__bf16)b.w;
        *(bf16x8*)(dst + i) = o;
        return;
    }
    const float* W = (z == 0) ? Wq : ((z == 1) ? Wk : Wv);
    __bf16* dst = Wt + (size_t)z * E * E;
    __shared__ __align__(16) float t[64][65];
    const int tt = blockIdx.x - 2048;
    const int n0 = (tt & 15) * 64, k0 = (tt >> 4) * 64;
    const int r = threadIdx.x >> 2, c4 = threadIdx.x & 3;
#pragma unroll
    for (int j = 0; j < 4; ++j) {
        const float4 vv = *(const float4*)&W[(size_t)(k0 + r) * E + n0 + c4 * 16 + j * 4];
        t[r][c4 * 16 + j * 4 + 0] = vv.x;
        t[r][c4 * 16 + j * 4 + 1] = vv.y;
        t[r][c4 * 16 + j * 4 + 2] = vv.z;
        t[r][c4 * 16 + j * 4 + 3] = vv.w;
    }
    __syncthreads();
    bf16x8 o0, o1;
#pragma unroll
    for (int j = 0; j < 8; ++j) {
        o0[j] = (__bf16)t[c4 * 16 + j][r];
        o1[j] = (__bf16)t[c4 * 16 + 8 + j][r];
    }
    *(bf16x8*)&dst[(size_t)(n0 + r) * E + k0 + c4 * 16] = o0;
    *(bf16x8*)&dst[(size_t)(n0 + r) * E + k0 + c4 * 16 + 8] = o1;
}

// ===== BK=32 GEMM: 3-slot triple-buffer + counted vmcnt + 1 barrier/tile, XCD-local =====
// R14 post-mortem locks in: separate convert pass beats f32-A-in-GEMM (R8/9/10/14).
// This round combines the two individually-best levers, never yet tested together:
//   - R13's occupancy (small LDS): 48KB total -> 3 blocks/CU = 12 waves/CU TLP
//   - R11's counted-vmcnt prefetch: 2-tile-deep pipeline, never drain to 0 in loop
// 256 thr = 4 waves (2Mx2N), per-wave 64x64, BK=32 -> 32 K-tiles, slots %3.
// Per tile T: issue stage(T+2) [A 2 + B 2 gload_lds]; frag-read slot T%3 (compiler
// emits lgkmcnt before MFMA); 16 MFMA; vmcnt(4) retires slot-(T+1)'s 4 loads
// (leaves T+2's 4 in flight); raw s_barrier publishes cross-wave.
// Slot safety: stage at T writes slot (T+2)%3 = slot read at tile T-1; those reads
// drained before T-1's closing barrier, and the barrier orders ALL waves' reads
// before ANY wave's T-stage writes. vmcnt ledger: steady 8 outstanding; prologue
// stages t0,t1 (8) -> vmcnt(4); T=30 no stage -> vmcnt(0); T=31 clean.
// Grid (32,8,3): bx = m-panel = XCD selector (A panels XCD-local, 63MB total).
// Swizzle (R13-verified): LDS slot16 s at row r holds global col16 s^(r&3).
__global__ __launch_bounds__(256) void gemm_qkv(const __bf16* __restrict__ Xb,
                                                const __bf16* __restrict__ Wt,
                                                const float* __restrict__ bq,
                                                const float* __restrict__ bk,
                                                const float* __restrict__ bv,
                                                __bf16* __restrict__ Cb) {
    const int z = blockIdx.z;
    const __bf16* A = Xb + (size_t)z * ROWS * E;
    const __bf16* Bm = Wt + (size_t)z * E * E;
    __bf16* C = Cb + (size_t)z * ROWS * E;
    const float* bias = (z == 0) ? bq : ((z == 1) ? bk : bv);
    const float alpha = (z == 0) ? 0.03125f : 1.0f;  // E^-0.5 = 1/32 for Q
    const int m0 = blockIdx.x * 128, n0 = blockIdx.y * 128;   // bx = m = XCD selector
    __shared__ __align__(16) __bf16 lsA[3][128 * 32];   // 3 x 8 KiB
    __shared__ __align__(16) __bf16 lsB[3][128 * 32];   // 3 x 8 KiB  (48 KiB total)
    const int tid = threadIdx.x;
    const int ln = tid & 63, wv = tid >> 6;
    const int lr = ln & 15, kg = ln >> 4;
    const int wm = (wv >> 1) * 64, wn = (wv & 1) * 64;
    // pre-swizzled source col16: thread writes LDS slot ln&3 at row (idx>>2),
    // row&3 = (tid>>2)&3 (i*256 contributes 0 mod 4 to row... i*64 ≡ 0 mod 4).
    const int cs = (((ln & 3) ^ ((tid >> 2) & 3)) << 3);   // bf16 elements

#define STAGE(T_, slot_)                                                          \
    {                                                                             \
        const int kt_ = (T_) * 32;                                                \
        _Pragma("unroll") for (int i = 0; i < 2; ++i) {                           \
            const int idx = i * 256 + tid;                                        \
            const int row = idx >> 2;                                             \
            gload16(A + (size_t)(m0 + row) * E + kt_ + cs,                        \
                    (char*)lsA[slot_] + idx * 16);                                \
        }                                                                         \
        _Pragma("unroll") for (int i = 0; i < 2; ++i) {                           \
            const int idx = i * 256 + tid;                                        \
            const int row = idx >> 2;                                             \
            gload16(Bm + (size_t)(n0 + row) * E + kt_ + cs,                       \
                    (char*)lsB[slot_] + idx * 16);                                \
        }                                                                         \
    }

    // prologue: tiles 0,1 -> slots 0,1; retire tile-0's 4 loads; publish.
    STAGE(0, 0);
    STAGE(1, 1);
    asm volatile("s_waitcnt vmcnt(4)" ::: "memory");
    __builtin_amdgcn_s_barrier();

    f32x4 acc[4][4] = {};
    for (int T = 0; T < 32; ++T) {
        const int cur = T % 3;
        if (T <= 29) { const int nxt = (T + 2) % 3; STAGE(T, /*dummy*/ nxt); }
        // NOTE: STAGE macro uses T_ for kt; need T+2 here -> re-expand properly:
        // (handled below by correct invocation; see STAGE2)
        bf16x8 af[4], bfr[4];
#pragma unroll
        for (int mi = 0; mi < 4; ++mi) {
            const int r = wm + mi * 16 + lr;
            af[mi] = *(const bf16x8*)((const char*)lsA[cur] + r * 64 + ((kg ^ (r & 3)) << 4));
        }
#pragma unroll
        for (int ni = 0; ni < 4; ++ni) {
            const int r = wn + ni * 16 + lr;
            bfr[ni] = *(const bf16x8*)((const char*)lsB[cur] + r * 64 + ((kg ^ (r & 3)) << 4));
        }
        __builtin_amdgcn_s_setprio(1);
#pragma unroll
        for (int mi = 0; mi < 4; ++mi)
#pragma unroll
            for (int ni = 0; ni < 4; ++ni)
                acc[mi][ni] = __builtin_amdgcn_mfma_f32_16x16x32_bf16(af[mi], bfr[ni], acc[mi][ni], 0, 0, 0);
        __builtin_amdgcn_s_setprio(0);
        if (T <= 29)      { asm volatile("s_waitcnt vmcnt(4)" ::: "memory"); }
        else if (T == 30) { asm volatile("s_waitcnt vmcnt(0)" ::: "memory"); }
        if (T <= 30) __builtin_amdgcn_s_barrier();
    }
#undef STAGE

    // epilogue: D row = kg*4+rr (M side), col = lr (N side)
#pragma unroll
    for (int mi = 0; mi < 4; ++mi)
#pragma unroll
        for (int ni = 0; ni < 4; ++ni) {
            const int col = n0 + wn + ni * 16 + lr;
            const int rbase = m0 + wm + mi * 16 + kg * 4;
            const float bcol = bias[col];
#pragma unroll
            for (int rr = 0; rr < 4; ++rr)
                C[(size_t)(rbase + rr) * E + col] = (__bf16)((acc[mi][ni][rr] + bcol) * alpha);
        }
}

// The STAGE invocation inside the loop must stage tile T+2, not T.  To keep the
// macro simple and the ledger exact, gemm_qkv above is superseded by gemm_qkv2
// below (identical except the corrected in-loop STAGE(T+2, nxt)); kernel_launch
// launches gemm_qkv2.
__global__ __launch_bounds__(256) void gemm_qkv2(const __bf16* __restrict__ Xb,
                                                 const __bf16* __restrict__ Wt,
                                                 const float* __restrict__ bq,
                                                 const float* __restrict__ bk,
                                                 const float* __restrict__ bv,
                                                 __bf16* __restrict__ Cb) {
    const int z = blockIdx.z;
    const __bf16* A = Xb + (size_t)z * ROWS * E;
    const __bf16* Bm = Wt + (size_t)z * E * E;
    __bf16* C = Cb + (size_t)z * ROWS * E;
    const float* bias = (z == 0) ? bq : ((z == 1) ? bk : bv);
    const float alpha = (z == 0) ? 0.03125f : 1.0f;
    const int m0 = blockIdx.x * 128, n0 = blockIdx.y * 128;   // bx = m = XCD selector
    __shared__ __align__(16) __bf16 lsA[3][128 * 32];
    __shared__ __align__(16) __bf16 lsB[3][128 * 32];
    const int tid = threadIdx.x;
    const int ln = tid & 63, wv = tid >> 6;
    const int lr = ln & 15, kg = ln >> 4;
    const int wm = (wv >> 1) * 64, wn = (wv & 1) * 64;
    const int cs = (((ln & 3) ^ ((tid >> 2) & 3)) << 3);

#define STAGE2(KT, slot_)                                                         \
    {                                                                             \
        _Pragma("unroll") for (int i = 0; i < 2; ++i) {                           \
            const int idx = i * 256 + tid;                                        \
            const int row = idx >> 2;                                             \
            gload16(A + (size_t)(m0 + row) * E + (KT) + cs,                       \
                    (char*)lsA[slot_] + idx * 16);                                \
        }                                                                         \
        _Pragma("unroll") for (int i = 0; i < 2; ++i) {                           \
            const int idx = i * 256 + tid;                                        \
            const int row = idx >> 2;                                             \
            gload16(Bm + (size_t)(n0 + row) * E + (KT) + cs,                      \
                    (char*)lsB[slot_] + idx * 16);                                \
        }                                                                         \
    }

    STAGE2(0, 0);
    STAGE2(32, 1);
    asm volatile("s_waitcnt vmcnt(4)" ::: "memory");
    __builtin_amdgcn_s_barrier();

    f32x4 acc[4][4] = {};
    for (int T = 0; T < 32; ++T) {
        const int cur = T % 3;
        if (T <= 29) STAGE2((T + 2) * 32, (T + 2) % 3);
        bf16x8 af[4], bfr[4];
#pragma unroll
        for (int mi = 0; mi < 4; ++mi) {
            const int r = wm + mi * 16 + lr;
            af[mi] = *(const bf16x8*)((const char*)lsA[cur] + r * 64 + ((kg ^ (r & 3)) << 4));
        }
#pragma unroll
        for (int ni = 0; ni < 4; ++ni) {
            const int r = wn + ni * 16 + lr;
            bfr[ni] = *(const bf16x8*)((const char*)lsB[cur] + r * 64 + ((kg ^ (r & 3)) << 4));
        }
        __builtin_amdgcn_s_setprio(1);
#pragma unroll
        for (int mi = 0; mi < 4; ++mi)
#pragma unroll
            for (int ni = 0; ni < 4; ++ni)
                acc[mi][ni] = __builtin_amdgcn_mfma_f32_16x16x32_bf16(af[mi], bfr[ni], acc[mi][ni], 0, 0, 0);
        __builtin_amdgcn_s_setprio(0);
        if (T <= 29)      { asm volatile("s_waitcnt vmcnt(4)" ::: "memory"); }
        else if (T == 30) { asm volatile("s_waitcnt vmcnt(0)" ::: "memory"); }
        if (T <= 30) __builtin_amdgcn_s_barrier();
    }
#undef STAGE2

#pragma unroll
    for (int mi = 0; mi < 4; ++mi)
#pragma unroll
        for (int ni = 0; ni < 4; ++ni) {
            const int col = n0 + wn + ni * 16 + lr;
            const int rbase = m0 + wm + mi * 16 + kg * 4;
            const float bcol = bias[col];
#pragma unroll
            for (int rr = 0; rr < 4; ++rr)
                C[(size_t)(rbase + rr) * E + col] = (__bf16)((acc[mi][ni][rr] + bcol) * alpha);
        }
}

// ---------------- per-(batch,head) MFMA reduction over a 128-t slice ----------------
__global__ __launch_bounds__(256) void reduce_kv(const __bf16* __restrict__ Kb,
                                                 const __bf16* __restrict__ Vb,
                                                 float* __restrict__ Mpart,
                                                 float* __restrict__ ksumP,
                                                 float* __restrict__ vsumP) {
    const int bh = blockIdx.x, b = bh >> 4, h = bh & 15;
    const int ts = blockIdx.y;
    const int t0 = ts * 128;
    __shared__ __align__(16) __bf16 sK[128 * 64];   // 16 KiB, swizzled
    __shared__ __align__(16) __bf16 sV[128 * 64];   // 16 KiB, swizzled
    __shared__ float red_k[4][64];
    __shared__ float red_v[4][64];
    const int tid = threadIdx.x;
    const int lane = tid & 63, wave = tid >> 6;
    const int lr = lane & 15, kg = lane >> 4;

    float vk[8] = {}, vv[8] = {};
    const int d0 = (tid & 7) * 8;
#pragma unroll
    for (int i = 0; i < 4; ++i) {
        const int t = i * 32 + (tid >> 3);
        const size_t g = (size_t)((t0 + t) * 2 + b) * E + h * 64 + d0;
        const bf16x8 kv = *(const bf16x8*)&Kb[g];
        const bf16x8 vvv = *(const bf16x8*)&Vb[g];
        const int lo = (t * 128 + d0 * 2) ^ (wave << 5);
        *(bf16x8*)((char*)sK + lo) = kv;
        *(bf16x8*)((char*)sV + lo) = vvv;
#pragma unroll
        for (int j = 0; j < 8; ++j) { vk[j] += (float)kv[j]; vv[j] += (float)vvv[j]; }
    }
#pragma unroll
    for (int m = 8; m <= 32; m <<= 1)
#pragma unroll
        for (int j = 0; j < 8; ++j) {
            vk[j] += __shfl_xor(vk[j], m, 64);
            vv[j] += __shfl_xor(vv[j], m, 64);
        }
    if (lane < 8)
#pragma unroll
        for (int j = 0; j < 8; ++j) {
            red_k[wave][lane * 8 + j] = vk[j];
            red_v[wave][lane * 8 + j] = vv[j];
        }
    __syncthreads();

    f32x4 acc[4] = {};
#pragma unroll
    for (int kt = 0; kt < 4; ++kt) {
        const int tb = kt * 32;
        bf16x8 afr, bfr[4];
        const char* pv = (const char*)sV + (((tb + kg * 8) * 128 + (wave * 16 + lr) * 2) ^ (kg << 5));
#pragma unroll
        for (int j = 0; j < 8; ++j) afr[j] = *(const __bf16*)(pv + j * 128);
#pragma unroll
        for (int ni = 0; ni < 4; ++ni) {
            const char* pk = (const char*)sK + (((tb + kg * 8) * 128 + (ni * 16 + lr) * 2) ^ (kg << 5));
#pragma unroll
            for (int j = 0; j < 8; ++j) bfr[ni][j] = *(const __bf16*)(pk + j * 128);
        }
#pragma unroll
        for (int ni = 0; ni < 4; ++ni)
            acc[ni] = __builtin_amdgcn_mfma_f32_16x16x32_bf16(afr, bfr[ni], acc[ni], 0, 0, 0);
    }

    float* Mp = Mpart + ((size_t)bh * 16 + ts) * 4096;
#pragma unroll
    for (int ni = 0; ni < 4; ++ni)
#pragma unroll
        for (int rr = 0; rr < 4; ++rr)
            Mp[(wave * 16 + kg * 4 + rr) * 64 + ni * 16 + lr] = acc[ni][rr];
    if (tid < 64)
        ksumP[(bh * 16 + ts) * 64 + tid] = red_k[0][tid] + red_k[1][tid] + red_k[2][tid] + red_k[3][tid];
    else if (tid < 128) {
        const int d = tid - 64;
        vsumP[(bh * 16 + ts) * 64 + d] = red_v[0][d] + red_v[1][d] + red_v[2][d] + red_v[3][d];
    }
}

// ---------------- combine the 16 t-split partials ----------------
__global__ __launch_bounds__(256) void combine_m(const float* __restrict__ Mpart,
                                                 const float* __restrict__ ksumP,
                                                 const float* __restrict__ vsumP,
                                                 float* __restrict__ Mt,
                                                 float* __restrict__ ksum,
                                                 float* __restrict__ vsum) {
    const int blk = blockIdx.x, tid = threadIdx.x;
    if (blk < 256) {
        const int e2 = (blk * 256 + tid) * 2;          // 131072 Mt elements, 2/thread
        const int bh = e2 >> 12, r = e2 & 4095;
        const float* src = Mpart + (size_t)bh * 16 * 4096 + r;
        float s0 = 0.f, s1 = 0.f;
#pragma unroll
        for (int ts = 0; ts < 16; ++ts) {
            s0 += src[ts * 4096];
            s1 += src[ts * 4096 + 1];
        }
        Mt[(size_t)bh * 4096 + r] = s0;
        Mt[(size_t)bh * 4096 + r + 1] = s1;
    } else if (blk < 264) {
        const int idx = (blk - 256) * 256 + tid;       // 2048 ksum elements
        const int bh = idx >> 6, d = idx & 63;
        float s = 0.f;
#pragma unroll
        for (int ts = 0; ts < 16; ++ts) s += ksumP[bh * 1024 + ts * 64 + d];
        ksum[idx] = s;
    } else {
        const int idx = (blk - 264) * 256 + tid;       // 2048 vsum elements
        const int bh = idx >> 6, d = idx & 63;
        float s = 0.f;
#pragma unroll
        for (int ts = 0; ts < 16; ++ts) s += vsumP[bh * 1024 + ts * 64 + d];
        vsum[idx] = s;
    }
}

// ---------------- epilogue: out[r, h*64+d2] = (v_sum[d2] + sum_d1 Q[r,d1]*M[d1][d2]) / Z_r ----
__global__ __launch_bounds__(256) void taylor_out(const __bf16* __restrict__ Qb,
                                                  const float* __restrict__ Mt,
                                                  const float* __restrict__ ksum,
                                                  const float* __restrict__ vsum,
                                                  float* __restrict__ out) {
    const int b = blockIdx.y;
    const int lblk = blockIdx.x * 16;
    const int tid = threadIdx.x, lane = tid & 63, wave = tid >> 6;
    const int lr = lane & 15, kg = lane >> 4;
    __shared__ __align__(16) __bf16 sM[4][4096];  // 4 heads' Mt (bf16, swizzled), 32 KiB
    for (int hh = 0; hh < 4; ++hh) {
        __syncthreads();
#pragma unroll
        for (int i = 0; i < 8; ++i) {
            const int idx = i * 256 + tid;  // 0..2047 chunks of 8 floats
            const int hseg = idx >> 9, rem = idx & 511;
            const float* src = &Mt[(size_t)(b * 16 + hseg * 4 + hh) * 4096 + rem * 8];
            const float4 mA = *(const float4*)src;
            const float4 mB = *(const float4*)(src + 4);
            bf16x8 o;
            o[0] = (__bf16)mA.x; o[1] = (__bf16)mA.y; o[2] = (__bf16)mA.z; o[3] = (__bf16)mA.w;
            o[4] = (__bf16)mB.x; o[5] = (__bf16)mB.y; o[6] = (__bf16)mB.z; o[7] = (__bf16)mB.w;
            *(bf16x8*)((char*)&sM[hseg][0] + SWZ(rem * 16)) = o;
        }
        __syncthreads();
        const int h = wave * 4 + hh;
        const int bh = b * 16 + h;
        const int rA = (lblk + lr) * 2 + b;
        const bf16x8 a0 = *(const bf16x8*)&Qb[(size_t)rA * E + h * 64 + kg * 8];
        const bf16x8 a1 = *(const bf16x8*)&Qb[(size_t)rA * E + h * 64 + 32 + kg * 8];
        float p = 0.f;
        const float* ks = &ksum[bh * 64];
#pragma unroll
        for (int j = 0; j < 8; ++j)
            p += (float)a0[j] * ks[kg * 8 + j] + (float)a1[j] * ks[32 + kg * 8 + j];
        p += __shfl_xor(p, 16, 64);
        p += __shfl_xor(p, 32, 64);
        const float Z = 2048.0f + p;
        f32x4 acc[4] = {};
#pragma unroll
        for (int ni = 0; ni < 4; ++ni) {
            const int byt0 = (ni * 16 + lr) * 128 + kg * 16;
            const bf16x8 b0 = *(const bf16x8*)((const char*)&sM[wave][0] + SWZ(byt0));
            const bf16x8 b1 = *(const bf16x8*)((const char*)&sM[wave][0] + SWZ(byt0 + 64));
            acc[ni] = __builtin_amdgcn_mfma_f32_16x16x32_bf16(a0, b0, acc[ni], 0, 0, 0);
            acc[ni] = __builtin_amdgcn_mfma_f32_16x16x32_bf16(a1, b1, acc[ni], 0, 0, 0);
        }
        float invZ[4];
#pragma unroll
        for (int rr = 0; rr < 4; ++rr) invZ[rr] = 1.0f / __shfl(Z, kg * 4 + rr, 64);
        const float* vs = &vsum[bh * 64];
#pragma unroll
        for (int ni = 0; ni < 4; ++ni)
#pragma unroll
            for (int rr = 0; rr < 4; ++rr) {
                const int l_out = lblk + kg * 4 + rr;
                out[(size_t)(l_out * 2 + b) * E + h * 64 + ni * 16 + lr] =
                    (vs[ni * 16 + lr] + acc[ni][rr]) * invZ[rr];
            }
    }
}

extern "C" void kernel_launch(void* const* d_in, const int* in_sizes, int n_in,
                              void* d_out, int out_size, void* d_ws, size_t ws_size,
                              hipStream_t stream) {
    const float* q  = (const float*)d_in[0];
    const float* k  = (const float*)d_in[1];
    const float* v  = (const float*)d_in[2];
    const float* Wq = (const float*)d_in[3];
    const float* bq = (const float*)d_in[4];
    const float* Wk = (const float*)d_in[5];
    const float* bk = (const float*)d_in[6];
    const float* Wv = (const float*)d_in[7];
    const float* bv = (const float*)d_in[8];
    float* out = (float*)d_out;
    char* w = (char*)d_ws;
    // workspace layout (~57 MB)
    __bf16* Xb = (__bf16*)(w);               // 3 x 4096x1024 bf16   (24 MiB)
    __bf16* Wt = (__bf16*)(w + 25165824);    // 3 x 1024x1024 bf16   ( 6 MiB)
    __bf16* Cb = (__bf16*)(w + 31457280);    // Q,K,V bf16           (24 MiB)
    float* Mt   = (float*)(w + 56623104);    // 32 x 64 x 64 f32 (Mt[d2][d1])
    float* ksum = (float*)(w + 57147392);    // 32 x 64
    float* vsum = (float*)(w + 57155584);    // 32 x 64
    // reduction partials overlap the Xb region (Xb is dead after gemm)
    float* Mpart = (float*)(w);              // 32 x 16 x 4096 f32 (8 MiB)
    float* ksumP = (float*)(w + 8388608);    // 32 x 16 x 64 f32
    float* vsumP = (float*)(w + 8519680);    // 32 x 16 x 64 f32

    prep<<<dim3(2304, 3), 256, 0, stream>>>(q, k, v, Wq, Wk, Wv, Xb, Wt);
    gemm_qkv2<<<dim3(32, 8, 3), 256, 0, stream>>>(Xb, Wt, bq, bk, bv, Cb);
    reduce_kv<<<dim3(32, 16), 256, 0, stream>>>(Cb + (size_t)ROWS * E,
                                                Cb + 2 * (size_t)ROWS * E, Mpart, ksumP, vsumP);
    combine_m<<<272, 256, 0, stream>>>(Mpart, ksumP, vsumP, Mt, ksum, vsum);
    taylor_out<<<dim3(128, 2), 256, 0, stream>>>(Cb, Mt, ksum, vsum, out);
}

// Round 16
// 71.599 us; speedup vs baseline: 1.0928x; 1.0928x over previous
//
#include <hip/hip_runtime.h>
#include <hip/hip_bf16.h>

// Problem constants
#define L_SEQ 2048
#define BATCH 2
#define ROWS 4096          // L*B, row index = l*2 + b
#define E 1024
#define NH 16
#define HD 64

typedef __attribute__((ext_vector_type(4))) float f32x4;
typedef __attribute__((ext_vector_type(8))) __bf16 bf16x8;

// XOR swizzle for 128-byte-row LDS tiles (break same-bank column reads)
#define SWZ(byt) ((byt) ^ ((((byt) >> 7) & 7) << 4))

__device__ __forceinline__ void gload16(const void* g, void* l) {
    __builtin_amdgcn_global_load_lds((const __attribute__((address_space(1))) void*)g,
                                     (__attribute__((address_space(3))) void*)l,
                                     16, 0, 0);
}

// ---------------- fused: f32->bf16 convert of q/k/v  +  W transpose to bf16 ----------------
__global__ __launch_bounds__(256) void prep(const float* __restrict__ q,
                                            const float* __restrict__ k,
                                            const float* __restrict__ v,
                                            const float* __restrict__ Wq,
                                            const float* __restrict__ Wk,
                                            const float* __restrict__ Wv,
                                            __bf16* __restrict__ Xb,
                                            __bf16* __restrict__ Wt) {
    const int z = blockIdx.y;
    if (blockIdx.x < 2048) {
        const float* src = (z == 0) ? q : ((z == 1) ? k : v);
        __bf16* dst = Xb + (size_t)z * ROWS * E;
        const size_t i = ((size_t)blockIdx.x * 256 + threadIdx.x) * 8;
        const float4 a = *(const float4*)(src + i);
        const float4 b = *(const float4*)(src + i + 4);
        bf16x8 o;
        o[0] = (__bf16)a.x; o[1] = (__bf16)a.y; o[2] = (__bf16)a.z; o[3] = (__bf16)a.w;
        o[4] = (__bf16)b.x; o[5] = (__bf16)b.y; o[6] = (__bf16)b.z; o[7] = (__bf16)b.w;
        *(bf16x8*)(dst + i) = o;
        return;
    }
    const float* W = (z == 0) ? Wq : ((z == 1) ? Wk : Wv);
    __bf16* dst = Wt + (size_t)z * E * E;
    __shared__ __align__(16) float t[64][65];
    const int tt = blockIdx.x - 2048;
    const int n0 = (tt & 15) * 64, k0 = (tt >> 4) * 64;
    const int r = threadIdx.x >> 2, c4 = threadIdx.x & 3;
#pragma unroll
    for (int j = 0; j < 4; ++j) {
        const float4 vv = *(const float4*)&W[(size_t)(k0 + r) * E + n0 + c4 * 16 + j * 4];
        t[r][c4 * 16 + j * 4 + 0] = vv.x;
        t[r][c4 * 16 + j * 4 + 1] = vv.y;
        t[r][c4 * 16 + j * 4 + 2] = vv.z;
        t[r][c4 * 16 + j * 4 + 3] = vv.w;
    }
    __syncthreads();
    bf16x8 o0, o1;
#pragma unroll
    for (int j = 0; j < 8; ++j) {
        o0[j] = (__bf16)t[c4 * 16 + j][r];
        o1[j] = (__bf16)t[c4 * 16 + 8 + j][r];
    }
    *(bf16x8*)&dst[(size_t)(n0 + r) * E + k0 + c4 * 16] = o0;
    *(bf16x8*)&dst[(size_t)(n0 + r) * E + k0 + c4 * 16 + 8] = o1;
}

// ===== R11 GEMM (session-best 43.2us): BK=64 dbuf counted-vmcnt, XCD-local A =====
// Six structures (R2/R5/R11/R12/R13/R15) all land 43-46us for this skinny shape
// (M=4096,N=K=1024, 768 tiles): structural floor ~600 TF. This is the fastest.
// 256 thr = 4 waves (2Mx2N), per-wave 64x64, BK=64 -> 16 K-tiles. LDS 64KB:
// A[2][128][64] + B[2][128][64] bf16, slot16 = c16^(row&7) swizzle via
// pre-swizzled global source (linear gload_lds dest) + swizzled ds_read.
// Grid (32,8,3): bx = m-panel = XCD selector -> A panels XCD-local (63MB total).
// Per tile T (2 phases), R4/R5-verified race-free:
//   ph0: read A-frags(8)+B n0,1(4); stage B(T+1); BAR; lgkm0; prio1; 16 MFMA; prio0; BAR
//   ph1: read B n2,3(4); stage A(T+2)->slot T&1; BAR; lgkm0; prio1; 16 MFMA; prio0;
//        vmcnt(4) [retires A(T+1)+B(T+1); leaves A(T+2)]; BAR
// Tails: T=14 skips A(16), closes vmcnt(0); T=15 clean.
__device__ __forceinline__ void stage_tile(const __bf16* __restrict__ gsrc, int row0, int kcol,
                                           char* ldsdst, int wv, int ln) {
#pragma unroll
    for (int r = 0; r < 4; ++r) {
        const int rowg = row0 + r * 32 + wv * 8 + (ln >> 3);
        const int c16 = (ln & 7) ^ (ln >> 3);   // inverse-swizzled source column
        gload16(gsrc + (size_t)rowg * E + kcol + c16 * 8,
                ldsdst + r * 4096 + wv * 1024);
    }
}

__device__ __forceinline__ bf16x8 fragld(const char* base, int row, int kk, int kg) {
    return *(const bf16x8*)(base + row * 128 + ((((kk << 2) | kg) ^ (row & 7)) << 4));
}

#define PH_SYNC_BEGIN  __builtin_amdgcn_s_barrier(); \
                       asm volatile("s_waitcnt lgkmcnt(0)" ::: "memory"); \
                       __builtin_amdgcn_s_setprio(1);
#define PH_SYNC_END    __builtin_amdgcn_s_setprio(0); \
                       __builtin_amdgcn_s_barrier();

__global__ __launch_bounds__(256, 2) void gemm_qkv(const __bf16* __restrict__ Xb,
                                                   const __bf16* __restrict__ Wt,
                                                   const float* __restrict__ bq,
                                                   const float* __restrict__ bk,
                                                   const float* __restrict__ bv,
                                                   __bf16* __restrict__ Cb) {
    __shared__ __align__(16) char smem[65536];
    const int z = blockIdx.z;
    const __bf16* A = Xb + (size_t)z * ROWS * E;
    const __bf16* B = Wt + (size_t)z * E * E;
    __bf16* C = Cb + (size_t)z * ROWS * E;
    const float* bias = (z == 0) ? bq : ((z == 1) ? bk : bv);
    const float alpha = (z == 0) ? 0.03125f : 1.0f;  // E^-0.5 = 1/32 for Q
    const int m0 = blockIdx.x * 128, n0 = blockIdx.y * 128;   // bx = m = XCD selector
    const int tid = threadIdx.x, ln = tid & 63, wv = tid >> 6;
    const int lr = ln & 15, kg = ln >> 4;
    const int wm = (wv & 1) * 64, wn = (wv >> 1) * 64;
    char* LA0 = smem;            char* LA1 = smem + 16384;
    char* LB0 = smem + 32768;    char* LB1 = smem + 49152;

    // prologue: A(0), B(0), A(1)  (12 loads/thread-stream)
    stage_tile(A, m0, 0,  LA0, wv, ln);
    stage_tile(B, n0, 0,  LB0, wv, ln);
    stage_tile(A, m0, 64, LA1, wv, ln);
    asm volatile("s_waitcnt vmcnt(4)" ::: "memory");
    __builtin_amdgcn_s_barrier();

    f32x4 acc[4][4] = {};
    bf16x8 Af[4][2], Bf[2][2];

#define LOAD_B(nb) \
    _Pragma("unroll") for (int nn = 0; nn < 2; ++nn) \
    _Pragma("unroll") for (int kk = 0; kk < 2; ++kk) \
        Bf[nn][kk] = fragld(cB, wn + ((nb) + nn) * 16 + lr, kk, kg);
#define QUAD(q) \
    _Pragma("unroll") for (int m = 0; m < 4; ++m) \
    _Pragma("unroll") for (int nn = 0; nn < 2; ++nn) \
    _Pragma("unroll") for (int kk = 0; kk < 2; ++kk) \
        acc[m][2 * (q) + nn] = __builtin_amdgcn_mfma_f32_16x16x32_bf16(Af[m][kk], Bf[nn][kk], acc[m][2 * (q) + nn], 0, 0, 0);

    for (int T = 0; T < 16; ++T) {
        const char* cA = (T & 1) ? LA1 : LA0;
        const char* cB = (T & 1) ? LB1 : LB0;
        char* nB = (T & 1) ? LB0 : LB1;      // B(T+1) -> slot (T+1)&1
        char* nA = (T & 1) ? LA1 : LA0;      // A(T+2) -> slot T&1 (replace A(T))
        // ---- phase 0 ----
#pragma unroll
        for (int m = 0; m < 4; ++m)
#pragma unroll
            for (int kk = 0; kk < 2; ++kk)
                Af[m][kk] = fragld(cA, wm + m * 16 + lr, kk, kg);
        LOAD_B(0);
        if (T < 15) stage_tile(B, n0, (T + 1) * 64, nB, wv, ln);
        PH_SYNC_BEGIN; QUAD(0); PH_SYNC_END;
        // ---- phase 1 ----
        LOAD_B(2);
        if (T < 14) stage_tile(A, m0, (T + 2) * 64, nA, wv, ln);
        PH_SYNC_BEGIN; QUAD(1);
        __builtin_amdgcn_s_setprio(0);
        if (T < 14)       { asm volatile("s_waitcnt vmcnt(4)" ::: "memory"); }
        else if (T == 14) { asm volatile("s_waitcnt vmcnt(0)" ::: "memory"); }
        __builtin_amdgcn_s_barrier();
    }
#undef LOAD_B
#undef QUAD

    // epilogue: D row = kg*4+rr (M side), col = lr (N side)
#pragma unroll
    for (int m = 0; m < 4; ++m) {
        const int rbase = m0 + wm + m * 16 + kg * 4;
#pragma unroll
        for (int n = 0; n < 4; ++n) {
            const int col = n0 + wn + n * 16 + lr;
            const float bcol = bias[col];
#pragma unroll
            for (int rr = 0; rr < 4; ++rr)
                C[(size_t)(rbase + rr) * E + col] = (__bf16)((acc[m][n][rr] + bcol) * alpha);
        }
    }
}

// ---------------- per-(batch,head) MFMA reduction over a 128-t slice ----------------
__global__ __launch_bounds__(256) void reduce_kv(const __bf16* __restrict__ Kb,
                                                 const __bf16* __restrict__ Vb,
                                                 float* __restrict__ Mpart,
                                                 float* __restrict__ ksumP,
                                                 float* __restrict__ vsumP) {
    const int bh = blockIdx.x, b = bh >> 4, h = bh & 15;
    const int ts = blockIdx.y;
    const int t0 = ts * 128;
    __shared__ __align__(16) __bf16 sK[128 * 64];   // 16 KiB, swizzled
    __shared__ __align__(16) __bf16 sV[128 * 64];   // 16 KiB, swizzled
    __shared__ float red_k[4][64];
    __shared__ float red_v[4][64];
    const int tid = threadIdx.x;
    const int lane = tid & 63, wave = tid >> 6;
    const int lr = lane & 15, kg = lane >> 4;

    float vk[8] = {}, vv[8] = {};
    const int d0 = (tid & 7) * 8;
#pragma unroll
    for (int i = 0; i < 4; ++i) {
        const int t = i * 32 + (tid >> 3);
        const size_t g = (size_t)((t0 + t) * 2 + b) * E + h * 64 + d0;
        const bf16x8 kv = *(const bf16x8*)&Kb[g];
        const bf16x8 vvv = *(const bf16x8*)&Vb[g];
        const int lo = (t * 128 + d0 * 2) ^ (wave << 5);
        *(bf16x8*)((char*)sK + lo) = kv;
        *(bf16x8*)((char*)sV + lo) = vvv;
#pragma unroll
        for (int j = 0; j < 8; ++j) { vk[j] += (float)kv[j]; vv[j] += (float)vvv[j]; }
    }
#pragma unroll
    for (int m = 8; m <= 32; m <<= 1)
#pragma unroll
        for (int j = 0; j < 8; ++j) {
            vk[j] += __shfl_xor(vk[j], m, 64);
            vv[j] += __shfl_xor(vv[j], m, 64);
        }
    if (lane < 8)
#pragma unroll
        for (int j = 0; j < 8; ++j) {
            red_k[wave][lane * 8 + j] = vk[j];
            red_v[wave][lane * 8 + j] = vv[j];
        }
    __syncthreads();

    f32x4 acc[4] = {};
#pragma unroll
    for (int kt = 0; kt < 4; ++kt) {
        const int tb = kt * 32;
        bf16x8 afr, bfr[4];
        const char* pv = (const char*)sV + (((tb + kg * 8) * 128 + (wave * 16 + lr) * 2) ^ (kg << 5));
#pragma unroll
        for (int j = 0; j < 8; ++j) afr[j] = *(const __bf16*)(pv + j * 128);
#pragma unroll
        for (int ni = 0; ni < 4; ++ni) {
            const char* pk = (const char*)sK + (((tb + kg * 8) * 128 + (ni * 16 + lr) * 2) ^ (kg << 5));
#pragma unroll
            for (int j = 0; j < 8; ++j) bfr[ni][j] = *(const __bf16*)(pk + j * 128);
        }
#pragma unroll
        for (int ni = 0; ni < 4; ++ni)
            acc[ni] = __builtin_amdgcn_mfma_f32_16x16x32_bf16(afr, bfr[ni], acc[ni], 0, 0, 0);
    }

    float* Mp = Mpart + ((size_t)bh * 16 + ts) * 4096;
#pragma unroll
    for (int ni = 0; ni < 4; ++ni)
#pragma unroll
        for (int rr = 0; rr < 4; ++rr)
            Mp[(wave * 16 + kg * 4 + rr) * 64 + ni * 16 + lr] = acc[ni][rr];
    if (tid < 64)
        ksumP[(bh * 16 + ts) * 64 + tid] = red_k[0][tid] + red_k[1][tid] + red_k[2][tid] + red_k[3][tid];
    else if (tid < 128) {
        const int d = tid - 64;
        vsumP[(bh * 16 + ts) * 64 + d] = red_v[0][d] + red_v[1][d] + red_v[2][d] + red_v[3][d];
    }
}

// ---------------- combine the 16 t-split partials ----------------
__global__ __launch_bounds__(256) void combine_m(const float* __restrict__ Mpart,
                                                 const float* __restrict__ ksumP,
                                                 const float* __restrict__ vsumP,
                                                 float* __restrict__ Mt,
                                                 float* __restrict__ ksum,
                                                 float* __restrict__ vsum) {
    const int blk = blockIdx.x, tid = threadIdx.x;
    if (blk < 256) {
        const int e2 = (blk * 256 + tid) * 2;          // 131072 Mt elements, 2/thread
        const int bh = e2 >> 12, r = e2 & 4095;
        const float* src = Mpart + (size_t)bh * 16 * 4096 + r;
        float s0 = 0.f, s1 = 0.f;
#pragma unroll
        for (int ts = 0; ts < 16; ++ts) {
            s0 += src[ts * 4096];
            s1 += src[ts * 4096 + 1];
        }
        Mt[(size_t)bh * 4096 + r] = s0;
        Mt[(size_t)bh * 4096 + r + 1] = s1;
    } else if (blk < 264) {
        const int idx = (blk - 256) * 256 + tid;       // 2048 ksum elements
        const int bh = idx >> 6, d = idx & 63;
        float s = 0.f;
#pragma unroll
        for (int ts = 0; ts < 16; ++ts) s += ksumP[bh * 1024 + ts * 64 + d];
        ksum[idx] = s;
    } else {
        const int idx = (blk - 264) * 256 + tid;       // 2048 vsum elements
        const int bh = idx >> 6, d = idx & 63;
        float s = 0.f;
#pragma unroll
        for (int ts = 0; ts < 16; ++ts) s += vsumP[bh * 1024 + ts * 64 + d];
        vsum[idx] = s;
    }
}

// ---------------- epilogue: out[r, h*64+d2] = (v_sum[d2] + sum_d1 Q[r,d1]*M[d1][d2]) / Z_r ----
__global__ __launch_bounds__(256) void taylor_out(const __bf16* __restrict__ Qb,
                                                  const float* __restrict__ Mt,
                                                  const float* __restrict__ ksum,
                                                  const float* __restrict__ vsum,
                                                  float* __restrict__ out) {
    const int b = blockIdx.y;
    const int lblk = blockIdx.x * 16;
    const int tid = threadIdx.x, lane = tid & 63, wave = tid >> 6;
    const int lr = lane & 15, kg = lane >> 4;
    __shared__ __align__(16) __bf16 sM[4][4096];  // 4 heads' Mt (bf16, swizzled), 32 KiB
    for (int hh = 0; hh < 4; ++hh) {
        __syncthreads();
#pragma unroll
        for (int i = 0; i < 8; ++i) {
            const int idx = i * 256 + tid;  // 0..2047 chunks of 8 floats
            const int hseg = idx >> 9, rem = idx & 511;
            const float* src = &Mt[(size_t)(b * 16 + hseg * 4 + hh) * 4096 + rem * 8];
            const float4 mA = *(const float4*)src;
            const float4 mB = *(const float4*)(src + 4);
            bf16x8 o;
            o[0] = (__bf16)mA.x; o[1] = (__bf16)mA.y; o[2] = (__bf16)mA.z; o[3] = (__bf16)mA.w;
            o[4] = (__bf16)mB.x; o[5] = (__bf16)mB.y; o[6] = (__bf16)mB.z; o[7] = (__bf16)mB.w;
            *(bf16x8*)((char*)&sM[hseg][0] + SWZ(rem * 16)) = o;
        }
        __syncthreads();
        const int h = wave * 4 + hh;
        const int bh = b * 16 + h;
        const int rA = (lblk + lr) * 2 + b;
        const bf16x8 a0 = *(const bf16x8*)&Qb[(size_t)rA * E + h * 64 + kg * 8];
        const bf16x8 a1 = *(const bf16x8*)&Qb[(size_t)rA * E + h * 64 + 32 + kg * 8];
        float p = 0.f;
        const float* ks = &ksum[bh * 64];
#pragma unroll
        for (int j = 0; j < 8; ++j)
            p += (float)a0[j] * ks[kg * 8 + j] + (float)a1[j] * ks[32 + kg * 8 + j];
        p += __shfl_xor(p, 16, 64);
        p += __shfl_xor(p, 32, 64);
        const float Z = 2048.0f + p;
        f32x4 acc[4] = {};
#pragma unroll
        for (int ni = 0; ni < 4; ++ni) {
            const int byt0 = (ni * 16 + lr) * 128 + kg * 16;
            const bf16x8 b0 = *(const bf16x8*)((const char*)&sM[wave][0] + SWZ(byt0));
            const bf16x8 b1 = *(const bf16x8*)((const char*)&sM[wave][0] + SWZ(byt0 + 64));
            acc[ni] = __builtin_amdgcn_mfma_f32_16x16x32_bf16(a0, b0, acc[ni], 0, 0, 0);
            acc[ni] = __builtin_amdgcn_mfma_f32_16x16x32_bf16(a1, b1, acc[ni], 0, 0, 0);
        }
        float invZ[4];
#pragma unroll
        for (int rr = 0; rr < 4; ++rr) invZ[rr] = 1.0f / __shfl(Z, kg * 4 + rr, 64);
        const float* vs = &vsum[bh * 64];
#pragma unroll
        for (int ni = 0; ni < 4; ++ni)
#pragma unroll
            for (int rr = 0; rr < 4; ++rr) {
                const int l_out = lblk + kg * 4 + rr;
                out[(size_t)(l_out * 2 + b) * E + h * 64 + ni * 16 + lr] =
                    (vs[ni * 16 + lr] + acc[ni][rr]) * invZ[rr];
            }
    }
}

extern "C" void kernel_launch(void* const* d_in, const int* in_sizes, int n_in,
                              void* d_out, int out_size, void* d_ws, size_t ws_size,
                              hipStream_t stream) {
    const float* q  = (const float*)d_in[0];
    const float* k  = (const float*)d_in[1];
    const float* v  = (const float*)d_in[2];
    const float* Wq = (const float*)d_in[3];
    const float* bq = (const float*)d_in[4];
    const float* Wk = (const float*)d_in[5];
    const float* bk = (const float*)d_in[6];
    const float* Wv = (const float*)d_in[7];
    const float* bv = (const float*)d_in[8];
    float* out = (float*)d_out;
    char* w = (char*)d_ws;
    // workspace layout (~57 MB)
    __bf16* Xb = (__bf16*)(w);               // 3 x 4096x1024 bf16   (24 MiB)
    __bf16* Wt = (__bf16*)(w + 25165824);    // 3 x 1024x1024 bf16   ( 6 MiB)
    __bf16* Cb = (__bf16*)(w + 31457280);    // Q,K,V bf16           (24 MiB)
    float* Mt   = (float*)(w + 56623104);    // 32 x 64 x 64 f32 (Mt[d2][d1])
    float* ksum = (float*)(w + 57147392);    // 32 x 64
    float* vsum = (float*)(w + 57155584);    // 32 x 64
    // reduction partials overlap the Xb region (Xb is dead after gemm_qkv)
    float* Mpart = (float*)(w);              // 32 x 16 x 4096 f32 (8 MiB)
    float* ksumP = (float*)(w + 8388608);    // 32 x 16 x 64 f32
    float* vsumP = (float*)(w + 8519680);    // 32 x 16 x 64 f32

    prep<<<dim3(2304, 3), 256, 0, stream>>>(q, k, v, Wq, Wk, Wv, Xb, Wt);
    gemm_qkv<<<dim3(32, 8, 3), 256, 0, stream>>>(Xb, Wt, bq, bk, bv, Cb);
    reduce_kv<<<dim3(32, 16), 256, 0, stream>>>(Cb + (size_t)ROWS * E,
                                                Cb + 2 * (size_t)ROWS * E, Mpart, ksumP, vsumP);
    combine_m<<<272, 256, 0, stream>>>(Mpart, ksumP, vsumP, Mt, ksum, vsum);
    taylor_out<<<dim3(128, 2), 256, 0, stream>>>(Cb, Mt, ksum, vsum, out);
}